// Round 8
// baseline (259.433 us; speedup 1.0000x reference)
//
#include <hip/hip_runtime.h>

#define INV_SQRT2f 0.70710678118654752440f

// Analysis filters; synthesis filter f[k] = AF[9-k] (time reversal).
// Polyphase synthesis: out[2q+p] = sum_{j=0..4} AF[9-(2j+p)] * x[(q+2-j) mod Nin]
__constant__ float c_FAR[2][2][10] = {
  {{0.0f, -0.08838834764832f, 0.08838834764832f, 0.69587998903400f, 0.69587998903400f,
    0.08838834764832f, -0.08838834764832f, 0.01122679215254f, 0.01122679215254f, 0.0f},
   {0.0f, -0.01122679215254f, 0.01122679215254f, 0.08838834764832f, 0.08838834764832f,
    -0.69587998903400f, 0.69587998903400f, -0.08838834764832f, -0.08838834764832f, 0.0f}},
  {{0.01122679215254f, 0.01122679215254f, -0.08838834764832f, 0.08838834764832f, 0.69587998903400f,
    0.69587998903400f, 0.08838834764832f, -0.08838834764832f, 0.0f, 0.0f},
   {0.0f, 0.0f, -0.08838834764832f, -0.08838834764832f, 0.69587998903400f,
    -0.69587998903400f, 0.08838834764832f, 0.08838834764832f, 0.01122679215254f, -0.01122679215254f}}
};
__constant__ float c_DUAL[2][2][10] = {
  {{0.03516384f, 0.0f, -0.08832942f, 0.23389032f, 0.76027237f,
    0.58751830f, 0.0f, -0.11430184f, 0.0f, 0.0f},
   {0.0f, 0.0f, -0.11430184f, 0.0f, 0.58751830f,
    -0.76027237f, 0.23389032f, 0.08832942f, 0.0f, -0.03516384f}},
  {{0.0f, 0.0f, -0.11430184f, 0.0f, 0.58751830f,
    0.76027237f, 0.23389032f, -0.08832942f, 0.0f, 0.03516384f},
   {-0.03516384f, 0.0f, 0.08832942f, 0.23389032f, -0.76027237f,
    0.58751830f, 0.0f, -0.11430184f, 0.0f, 0.0f}}
};

// ---- staging: 12x12 spatial halo tile x 16 ch = 576 float4, 256 threads ----
template<int NSZ>
__device__ __forceinline__ void stage_copy(const float* __restrict__ src, float* __restrict__ dst,
                                           int ih0, int iw0, int tid) {
  #pragma unroll
  for (int it = 0; it < 3; ++it) {
    int e = tid + (it << 8);
    if (it < 2 || e < 576) {
      int r = e / 48;
      int cc = e - r * 48;
      int gr = (ih0 + r - 2) & (NSZ - 1);
      int gc = (iw0 + (cc >> 2) - 2) & (NSZ - 1);
      float4 v = *reinterpret_cast<const float4*>(src + (((size_t)gr * NSZ + gc) << 4) + ((cc & 3) << 2));
      *reinterpret_cast<float4*>(dst + (e << 2)) = v;
    }
  }
}

template<int NSZ>
__device__ __forceinline__ void stage_mix(const float* __restrict__ A, const float* __restrict__ B,
                                          float sgn, float* __restrict__ dst,
                                          int ih0, int iw0, int tid) {
  #pragma unroll
  for (int it = 0; it < 3; ++it) {
    int e = tid + (it << 8);
    if (it < 2 || e < 576) {
      int r = e / 48;
      int cc = e - r * 48;
      int gr = (ih0 + r - 2) & (NSZ - 1);
      int gc = (iw0 + (cc >> 2) - 2) & (NSZ - 1);
      size_t off = (((size_t)gr * NSZ + gc) << 4) + ((cc & 3) << 2);
      float4 a = *reinterpret_cast<const float4*>(A + off);
      float4 b = *reinterpret_cast<const float4*>(B + off);
      float4 v;
      v.x = (a.x + sgn * b.x) * INV_SQRT2f;
      v.y = (a.y + sgn * b.y) * INV_SQRT2f;
      v.z = (a.z + sgn * b.z) * INV_SQRT2f;
      v.w = (a.w + sgn * b.w) * INV_SQRT2f;
      *reinterpret_cast<float4*>(dst + (e << 2)) = v;
    }
  }
}

// ---------------- Stage A: q-shift level (128 -> 256), unchanged from R7 ----------------
__global__ __launch_bounds__(256) void qshift_kernel(
    const float* __restrict__ w2, const float* __restrict__ loT, float* __restrict__ mid)
{
  __shared__ __align__(16) float sIn[4][12][12][16];

  const int tid = threadIdx.x;
  const int c = tid & 15;
  const int s = tid >> 4;
  const int tw = blockIdx.x;
  const int th = blockIdx.y;
  const int b  = blockIdx.z & 3;
  const int q  = blockIdx.z >> 2;
  const int m = q >> 1, n = q & 1;
  const int j1 = m ^ n;
  const float sgn = m ? -1.0f : 1.0f;
  const int ih0 = th * 8, iw0 = tw * 8;
  const size_t plane = (size_t)128 * 128 * 16;

  stage_copy<128>(loT + ((size_t)(m * 2 + n) * 4 + b) * plane, &sIn[0][0][0][0], ih0, iw0, tid);
  stage_mix<128>(w2 + ((size_t)((0 * 2 + j1) * 3 + 0) * 4 + b) * plane,
                 w2 + ((size_t)((1 * 2 + (1 ^ j1)) * 3 + 0) * 4 + b) * plane,
                 sgn, &sIn[1][0][0][0], ih0, iw0, tid);
  stage_mix<128>(w2 + ((size_t)((0 * 2 + j1) * 3 + 1) * 4 + b) * plane,
                 w2 + ((size_t)((1 * 2 + (1 ^ j1)) * 3 + 1) * 4 + b) * plane,
                 sgn, &sIn[2][0][0][0], ih0, iw0, tid);
  stage_mix<128>(w2 + ((size_t)((0 * 2 + j1) * 3 + 2) * 4 + b) * plane,
                 w2 + ((size_t)((1 * 2 + (1 ^ j1)) * 3 + 2) * 4 + b) * plane,
                 sgn, &sIn[3][0][0][0], ih0, iw0, tid);
  __syncthreads();

  const int pw = s & 1, qw = s >> 1;
  float flp[5], fhp[5];
  #pragma unroll
  for (int j = 0; j < 5; ++j) {
    flp[j] = c_DUAL[n][0][9 - (2 * j + pw)];
    fhp[j] = c_DUAL[n][1][9 - (2 * j + pw)];
  }
  float lo2[12], h2[12];
  #pragma unroll
  for (int r = 0; r < 12; ++r) {
    float lo_v = 0.f, h_v = 0.f;
    #pragma unroll
    for (int j = 0; j < 5; ++j) {
      int x = qw + 4 - j;
      lo_v += flp[j] * sIn[0][r][x][c] + fhp[j] * sIn[1][r][x][c];
      h_v  += flp[j] * sIn[2][r][x][c] + fhp[j] * sIn[3][r][x][c];
    }
    lo2[r] = lo_v;
    h2[r] = h_v;
  }

  float* outQ = mid + ((size_t)q * 4 + b) * (size_t)(256 * 256 * 16);
  #pragma unroll
  for (int nh = 0; nh < 16; ++nh) {
    int ph = nh & 1, qh = nh >> 1;
    float v = 0.f;
    #pragma unroll
    for (int j = 0; j < 5; ++j) {
      v += c_DUAL[m][0][9 - (2 * j + ph)] * lo2[qh + 4 - j]
         + c_DUAL[m][1][9 - (2 * j + ph)] * h2[qh + 4 - j];
    }
    outQ[(((size_t)(ih0 * 2 + nh)) * 256 + (size_t)(iw0 * 2 + s)) * 16 + c] = v;
  }
}

// ---------------- Stage B: Farras level (256 -> 512), register-prefetch pipeline ----------------
// Runtime q-loop; prefetch quadrant q+1's 7 raw planes into regs right after the
// LDS-write barrier, so HBM latency hides under q's col+row compute (T14).
// Mix (A +/- B)*inv_sqrt2 happens at ds_write time.
__global__ __launch_bounds__(256) void farras_kernel(
    const float* __restrict__ w1, const float* __restrict__ mid, float* __restrict__ out)
{
  __shared__ __align__(16) float sIn[4][12][12][16];
  float* const sInF = &sIn[0][0][0][0];

  const int tid = threadIdx.x;
  const int c = tid & 15;
  const int s = tid >> 4;
  const int tw = blockIdx.x;
  const int th = blockIdx.y;
  const int b  = blockIdx.z;
  const int ih0 = th * 8, iw0 = tw * 8;
  const size_t plane = (size_t)256 * 256 * 16;

  // Quadrant-invariant staging geometry (3 slots/thread; slot 2 active iff tid<64)
  int goff[3], eo[3];
  bool act[3];
  #pragma unroll
  for (int it = 0; it < 3; ++it) {
    int e = tid + (it << 8);
    act[it] = (it < 2) || (e < 576);
    int r = e / 48;
    int cc = e - r * 48;
    int gr = (ih0 + r - 2) & 255;
    int gc = (iw0 + (cc >> 2) - 2) & 255;
    goff[it] = ((gr * 256 + gc) << 4) + ((cc & 3) << 2);
    eo[it] = e << 2;
  }

  float4 gm[3], gA[3][3], gB[3][3];

  auto load_quad = [&](int q) {
    const int mm = q >> 1, nn = q & 1, jj = mm ^ nn;
    const float* pm = mid + ((size_t)q * 4 + b) * plane;
    #pragma unroll
    for (int it = 0; it < 3; ++it)
      if (act[it]) gm[it] = *reinterpret_cast<const float4*>(pm + goff[it]);
    #pragma unroll
    for (int o = 0; o < 3; ++o) {
      const float* pA = w1 + ((size_t)((0 * 2 + jj) * 3 + o) * 4 + b) * plane;
      const float* pB = w1 + ((size_t)((1 * 2 + (1 ^ jj)) * 3 + o) * 4 + b) * plane;
      #pragma unroll
      for (int it = 0; it < 3; ++it)
        if (act[it]) {
          gA[o][it] = *reinterpret_cast<const float4*>(pA + goff[it]);
          gB[o][it] = *reinterpret_cast<const float4*>(pB + goff[it]);
        }
    }
  };

  float acc[16];
  #pragma unroll
  for (int i = 0; i < 16; ++i) acc[i] = 0.f;

  const int pw = s & 1, qw = s >> 1;

  load_quad(0);  // prologue

  #pragma unroll 1
  for (int q = 0; q < 4; ++q) {
    const int m = q >> 1, n = q & 1;
    const float sgn = m ? -1.0f : 1.0f;

    __syncthreads();  // all waves done reading sIn from previous iteration

    // LDS-write phase: mix in regs -> 4 planes
    #pragma unroll
    for (int it = 0; it < 3; ++it)
      if (act[it]) {
        *reinterpret_cast<float4*>(sInF + 0 * 2304 + eo[it]) = gm[it];
        #pragma unroll
        for (int o = 0; o < 3; ++o) {
          float4 a = gA[o][it], bb = gB[o][it], v;
          v.x = (a.x + sgn * bb.x) * INV_SQRT2f;
          v.y = (a.y + sgn * bb.y) * INV_SQRT2f;
          v.z = (a.z + sgn * bb.z) * INV_SQRT2f;
          v.w = (a.w + sgn * bb.w) * INV_SQRT2f;
          *reinterpret_cast<float4*>(sInF + (1 + o) * 2304 + eo[it]) = v;
        }
      }
    __syncthreads();

    if (q < 3) load_quad(q + 1);  // issue next-quadrant loads; overlap with compute

    // Column pass, tree n filters
    float flp[5], fhp[5];
    #pragma unroll
    for (int j = 0; j < 5; ++j) {
      flp[j] = c_FAR[n][0][9 - (2 * j + pw)];
      fhp[j] = c_FAR[n][1][9 - (2 * j + pw)];
    }
    float lo2[12], h2[12];
    #pragma unroll
    for (int r = 0; r < 12; ++r) {
      float lo_v = 0.f, h_v = 0.f;
      #pragma unroll
      for (int j = 0; j < 5; ++j) {
        int x = qw + 4 - j;
        lo_v += flp[j] * sIn[0][r][x][c] + fhp[j] * sIn[1][r][x][c];
        h_v  += flp[j] * sIn[2][r][x][c] + fhp[j] * sIn[3][r][x][c];
      }
      lo2[r] = lo_v;
      h2[r] = h_v;
    }

    // Row pass, tree m filters; register gather -> accumulate
    #pragma unroll
    for (int nh = 0; nh < 16; ++nh) {
      int ph = nh & 1, qh = nh >> 1;
      float v = 0.f;
      #pragma unroll
      for (int j = 0; j < 5; ++j) {
        v += c_FAR[m][0][9 - (2 * j + ph)] * lo2[qh + 4 - j]
           + c_FAR[m][1][9 - (2 * j + ph)] * h2[qh + 4 - j];
      }
      acc[nh] += v;
    }
  }

  #pragma unroll
  for (int nh = 0; nh < 16; ++nh) {
    size_t gh = (size_t)(ih0 * 2 + nh);
    size_t gw = (size_t)(iw0 * 2 + s);
    out[(((size_t)b * 512 + gh) * 512 + gw) * 16 + c] = acc[nh] * 0.5f;
  }
}

extern "C" void kernel_launch(void* const* d_in, const int* in_sizes, int n_in,
                              void* d_out, int out_size, void* d_ws, size_t ws_size,
                              hipStream_t stream) {
  const float* w1 = (const float*)d_in[0];   // [2,2,3,4,256,256,16]
  const float* w2 = (const float*)d_in[1];   // [2,2,3,4,128,128,16]
  const float* lo = (const float*)d_in[2];   // [2,2,4,128,128,16]
  float* out = (float*)d_out;                // [4,512,512,16]
  float* mid = (float*)d_ws;                 // [4 quadrants][4][256][256][16] = 64 MiB

  qshift_kernel<<<dim3(16, 16, 16), 256, 0, stream>>>(w2, lo, mid);
  farras_kernel<<<dim3(32, 32, 4), 256, 0, stream>>>(w1, mid, out);
}